// Round 1
// baseline (153.180 us; speedup 1.0000x reference)
//
#include <hip/hip_runtime.h>
#include <hip/hip_bf16.h>

// out[i] = sum_k coeffs[k] * R_{n_k l_k}(r) * Y_{l_k m_k}(theta, phi)
// position: (OutN*n, 3) interleaved (r, theta, phi), fp32. Output fp32.
//
// Basis order (14): (1,0,0) (2,0,0) (2,1,-1) (2,1,0) (2,1,1) (3,0,0)
//                   (3,1,-1) (3,1,0) (3,1,1) (3,2,-2) (3,2,-1) (3,2,0) (3,2,1) (3,2,2)
//
// Radial norms (a0=1) folded to decimals:
//   R10 = 2 e^{-r}
//   R20 = 0.35355339059 e^{-r/2} (2 - r)          // 1/(2*sqrt(2))
//   R21 = 0.20412414523 e^{-r/2} r                // 1/sqrt(24)
//   R30 = 0.12830005982 e^{-r/3} (3 - 2r + (2/9) r^2)   // 2/sqrt(243)
//   R31 = 0.04536092116 e^{-r/3} r (8/3 - (4/9) r)      // 1/sqrt(486)
//   R32 = 0.00901600915 e^{-r/3} r^2              // (1/sqrt(2430))*(4/9)
// Real SH (Condon-Shortley folded):
//   Y00 = 0.28209479177
//   Y10 = 0.48860251190 ct
//   Y1,+-1 = 0.48860251190 * (-st) * {cos phi, sin phi}
//   Y20 = 0.94617469575 ct^2 - 0.31539156525
//   Y2,+-1 = -1.09254843059 ct st * {cos phi, sin phi}
//   Y2,+-2 = 0.54627421529 st^2 * {cos 2phi, sin 2phi}

__device__ __forceinline__ float eval_point(float r, float theta, float phi,
                                            const float* __restrict__ c) {
    float st, ct;
    __sincosf(theta, &st, &ct);      // theta in [0,pi] region => st == sqrt(1-ct^2)
    float sp, cp;
    __sincosf(phi, &sp, &cp);
    const float s2p = 2.0f * sp * cp;
    const float c2p = 2.0f * cp * cp - 1.0f;

    // exp(-r/6) and powers -> e^{-r}, e^{-r/2}, e^{-r/3}
    const float ex  = __expf(r * (-1.0f / 6.0f));
    const float ex2 = ex * ex;
    const float ex3 = ex2 * ex;
    const float e1  = ex3 * ex3;   // e^{-r}
    const float e2  = ex3;         // e^{-r/2}
    const float e3  = ex2;         // e^{-r/3}

    const float R10 = 2.0f * e1;
    const float R20 = 0.35355339059f * e2 * (2.0f - r);
    const float R21 = 0.20412414523f * e2 * r;
    const float R30 = 0.12830005982f * e3 * (3.0f + r * (-2.0f + 0.22222222222f * r));
    const float R31 = 0.04536092116f * e3 * r * (2.66666666667f - 0.44444444444f * r);
    const float R32 = 0.00901600915f * e3 * r * r;

    // l=0 (m=0)
    float acc = 0.28209479177f * (c[0] * R10 + c[1] * R20 + c[5] * R30);
    // l=1
    acc += 0.48860251190f * ct * (c[3] * R21 + c[7] * R31);
    acc -= 0.48860251190f * st * (sp * (c[2] * R21 + c[6] * R31)
                                + cp * (c[4] * R21 + c[8] * R31));
    // l=2 (all share R32)
    const float y20 = 0.94617469575f * ct * ct - 0.31539156525f;
    acc += R32 * (c[11] * y20
                  - 1.09254843059f * ct * st * (c[10] * sp + c[12] * cp)
                  + 0.54627421529f * st * st * (c[9] * s2p + c[13] * c2p));
    return acc;
}

__global__ __launch_bounds__(256) void orbitals_vec4(
    const float4* __restrict__ pos4,   // position viewed as float4
    const float* __restrict__ coeffs,  // 14 floats
    float4* __restrict__ out4,
    int groups)                        // number of 4-element groups
{
    const int g = blockIdx.x * blockDim.x + threadIdx.x;
    if (g >= groups) return;

    // 4 elements = 12 floats = 3 float4 loads (48B per lane, 16B aligned)
    const float4 a = pos4[3 * g + 0];
    const float4 b = pos4[3 * g + 1];
    const float4 d = pos4[3 * g + 2];

    float4 o;
    o.x = eval_point(a.x, a.y, a.z, coeffs);
    o.y = eval_point(a.w, b.x, b.y, coeffs);
    o.z = eval_point(b.z, b.w, d.x, coeffs);
    o.w = eval_point(d.y, d.z, d.w, coeffs);
    out4[g] = o;
}

__global__ void orbitals_tail(
    const float* __restrict__ pos,
    const float* __restrict__ coeffs,
    float* __restrict__ out,
    int start, int total)
{
    const int i = start + blockIdx.x * blockDim.x + threadIdx.x;
    if (i >= total) return;
    out[i] = eval_point(pos[3 * i + 0], pos[3 * i + 1], pos[3 * i + 2], coeffs);
}

extern "C" void kernel_launch(void* const* d_in, const int* in_sizes, int n_in,
                              void* d_out, int out_size, void* d_ws, size_t ws_size,
                              hipStream_t stream) {
    const float* pos    = (const float*)d_in[0];
    const float* coeffs = (const float*)d_in[1];
    float* out = (float*)d_out;

    const int total  = out_size;          // 8,388,608
    const int groups = total / 4;
    const int rem    = total - groups * 4;

    if (groups > 0) {
        const int block = 256;
        const int grid  = (groups + block - 1) / block;
        orbitals_vec4<<<grid, block, 0, stream>>>(
            (const float4*)pos, coeffs, (float4*)out, groups);
    }
    if (rem > 0) {
        orbitals_tail<<<1, 64, 0, stream>>>(pos, coeffs, out, groups * 4, total);
    }
}

// Round 2
// 152.105 us; speedup vs baseline: 1.0071x; 1.0071x over previous
//
#include <hip/hip_runtime.h>
#include <hip/hip_bf16.h>

// out[i] = sum_k coeffs[k] * R_{n_k l_k}(r) * Y_{l_k m_k}(theta, phi)
// position: (OutN*n, 3) interleaved (r, theta, phi), fp32. Output fp32.
//
// R1 load pattern change: the AoS stride-48B float4 loads were
// transaction-bound (~2.4 TB/s). Now each 256-thread block stages its
// 12 KB input chunk via 3 lane-contiguous float4 loads -> LDS -> each
// thread reads its own 48 B with 3x ds_read_b128.
//
// Radial norms (a0=1) folded to decimals:
//   R10 = 2 e^{-r}
//   R20 = 0.35355339059 e^{-r/2} (2 - r)
//   R21 = 0.20412414523 e^{-r/2} r
//   R30 = 0.12830005982 e^{-r/3} (3 - 2r + (2/9) r^2)
//   R31 = 0.04536092116 e^{-r/3} r (8/3 - (4/9) r)
//   R32 = 0.00901600915 e^{-r/3} r^2
// Real SH (Condon-Shortley folded):
//   Y00 = 0.28209479177 ; Y10 = 0.48860251190 ct
//   Y1,+-1 = -0.48860251190 st {sin,cos}(phi)
//   Y20 = 0.94617469575 ct^2 - 0.31539156525
//   Y2,+-1 = -1.09254843059 ct st {sin,cos}(phi)
//   Y2,+-2 = 0.54627421529 st^2 {sin,cos}(2 phi)

__device__ __forceinline__ float eval_point(float r, float theta, float phi,
                                            const float* __restrict__ c) {
    float st, ct;
    __sincosf(theta, &st, &ct);
    float sp, cp;
    __sincosf(phi, &sp, &cp);
    const float s2p = 2.0f * sp * cp;
    const float c2p = 2.0f * cp * cp - 1.0f;

    const float ex  = __expf(r * (-1.0f / 6.0f));
    const float ex2 = ex * ex;
    const float ex3 = ex2 * ex;
    const float e1  = ex3 * ex3;   // e^{-r}
    const float e2  = ex3;         // e^{-r/2}
    const float e3  = ex2;         // e^{-r/3}

    const float R10 = 2.0f * e1;
    const float R20 = 0.35355339059f * e2 * (2.0f - r);
    const float R21 = 0.20412414523f * e2 * r;
    const float R30 = 0.12830005982f * e3 * (3.0f + r * (-2.0f + 0.22222222222f * r));
    const float R31 = 0.04536092116f * e3 * r * (2.66666666667f - 0.44444444444f * r);
    const float R32 = 0.00901600915f * e3 * r * r;

    float acc = 0.28209479177f * (c[0] * R10 + c[1] * R20 + c[5] * R30);
    acc += 0.48860251190f * ct * (c[3] * R21 + c[7] * R31);
    acc -= 0.48860251190f * st * (sp * (c[2] * R21 + c[6] * R31)
                                + cp * (c[4] * R21 + c[8] * R31));
    const float y20 = 0.94617469575f * ct * ct - 0.31539156525f;
    acc += R32 * (c[11] * y20
                  - 1.09254843059f * ct * st * (c[10] * sp + c[12] * cp)
                  + 0.54627421529f * st * st * (c[9] * s2p + c[13] * c2p));
    return acc;
}

// Each block: 256 threads, 1024 elements, 12 KB staged through LDS.
__global__ __launch_bounds__(256) void orbitals_lds(
    const float4* __restrict__ pos4,   // position viewed as float4
    const float* __restrict__ coeffs,  // 14 floats
    float4* __restrict__ out4)
{
    __shared__ float4 smem[768];       // 12 KB
    const int t = threadIdx.x;
    const int base4 = blockIdx.x * 768;   // float4 index of block's chunk

    // Coalesced: lane-contiguous float4 loads (16 B/lane, 1 KiB/wave/instr)
#pragma unroll
    for (int k = 0; k < 3; ++k)
        smem[k * 256 + t] = pos4[base4 + k * 256 + t];
    __syncthreads();

    // Each thread's 4 elements = floats [12t, 12t+12) of the chunk
    const float4 a = smem[3 * t + 0];
    const float4 b = smem[3 * t + 1];
    const float4 d = smem[3 * t + 2];

    float4 o;
    o.x = eval_point(a.x, a.y, a.z, coeffs);
    o.y = eval_point(a.w, b.x, b.y, coeffs);
    o.z = eval_point(b.z, b.w, d.x, coeffs);
    o.w = eval_point(d.y, d.z, d.w, coeffs);
    out4[blockIdx.x * 256 + t] = o;    // coalesced 16 B/lane store
}

__global__ void orbitals_tail(
    const float* __restrict__ pos,
    const float* __restrict__ coeffs,
    float* __restrict__ out,
    int start, int total)
{
    const int i = start + blockIdx.x * blockDim.x + threadIdx.x;
    if (i >= total) return;
    out[i] = eval_point(pos[3 * i + 0], pos[3 * i + 1], pos[3 * i + 2], coeffs);
}

extern "C" void kernel_launch(void* const* d_in, const int* in_sizes, int n_in,
                              void* d_out, int out_size, void* d_ws, size_t ws_size,
                              hipStream_t stream) {
    const float* pos    = (const float*)d_in[0];
    const float* coeffs = (const float*)d_in[1];
    float* out = (float*)d_out;

    const int total = out_size;                 // 8,388,608 = 8192 * 1024
    const int full_blocks = total / 1024;       // blocks of 1024 elements
    const int done = full_blocks * 1024;
    const int rem = total - done;

    if (full_blocks > 0) {
        orbitals_lds<<<full_blocks, 256, 0, stream>>>(
            (const float4*)pos, coeffs, (float4*)out);
    }
    if (rem > 0) {
        const int block = 256;
        const int grid = (rem + block - 1) / block;
        orbitals_tail<<<grid, block, 0, stream>>>(pos, coeffs, out, done, total);
    }
}